// Round 9
// baseline (266.632 us; speedup 1.0000x reference)
//
#include <hip/hip_runtime.h>
#include <math.h>

// Problem constants (fixed by reference file)
#define BROWS 2048
#define NCOLS 16384
#define NT    1024                // 16 waves/block, 2 blocks/CU
#define F4R   (NCOLS / NT / 4)    // float4 per thread per row = 4
#define CCAP  1024                // per-row candidate capacity (zm-1 fallback can hit ~900)

typedef float f32x4 __attribute__((ext_vector_type(4)));   // native vec for nt-store

__global__ __launch_bounds__(NT, 8)   // VGPR<=64: zrA+zrB=32 data regs + ~20 temps
void entmax2(const float* __restrict__ in, float* __restrict__ outw,
             float* __restrict__ outn)
{
    __shared__ float candA[CCAP + 4], candB[CCAP + 4];  // 8.2 KB
    __shared__ float redA[4][16], redB[4][16];          // g-level partials
    __shared__ float redmA[16], redmB[16];              // max partials
    __shared__ float s_zmA, s_zmB, s_TA, s_TB, s_tauA, s_SA, s_tauB, s_SB;
    __shared__ int   s_cntA, s_cntB, s_nselA, s_nselB;

    const int pair = blockIdx.x;
    const int rowA = pair * 2, rowB = pair * 2 + 1;
    const int tid  = threadIdx.x;
    const int lane = tid & 63;
    const int wid  = tid >> 6;
    const float4* rpA = (const float4*)(in + (size_t)rowA * NCOLS);
    const float4* rpB = (const float4*)(in + (size_t)rowB * NCOLS);
    f32x4*        wpA = (f32x4*)(outw + (size_t)rowA * NCOLS);
    f32x4*        wpB = (f32x4*)(outw + (size_t)rowB * NCOLS);

    if (tid == 0) { s_cntA = 0; s_cntB = 0; s_nselA = 0; s_nselB = 0; }

    // ---- P1: load both rows into registers (z = x/2), per-wave maxes ----
    float4 zrA[F4R], zrB[F4R];
    #pragma unroll
    for (int it = 0; it < F4R; ++it) zrA[it] = rpA[it * NT + tid];
    #pragma unroll
    for (int it = 0; it < F4R; ++it) zrB[it] = rpB[it * NT + tid];
    float mA = -INFINITY, mB = -INFINITY;
    #pragma unroll
    for (int it = 0; it < F4R; ++it) {
        float4 a = zrA[it];
        a.x *= 0.5f; a.y *= 0.5f; a.z *= 0.5f; a.w *= 0.5f; zrA[it] = a;
        mA = fmaxf(mA, fmaxf(fmaxf(a.x, a.y), fmaxf(a.z, a.w)));
        float4 b = zrB[it];
        b.x *= 0.5f; b.y *= 0.5f; b.z *= 0.5f; b.w *= 0.5f; zrB[it] = b;
        mB = fmaxf(mB, fmaxf(fmaxf(b.x, b.y), fmaxf(b.z, b.w)));
    }
    #pragma unroll
    for (int off = 1; off < 64; off <<= 1) {
        mA = fmaxf(mA, __shfl_xor(mA, off));
        mB = fmaxf(mB, __shfl_xor(mB, off));
    }
    if (lane == 0) { redmA[wid] = mA; redmB[wid] = mB; }
    __syncthreads();                                           // B1
    if (wid == 0) {
        float v = (lane < 16) ? redmA[lane] : -INFINITY;
        #pragma unroll
        for (int off = 1; off < 16; off <<= 1) v = fmaxf(v, __shfl_xor(v, off));
        if (lane == 0) s_zmA = v;
    } else if (wid == 1) {
        float v = (lane < 16) ? redmB[lane] : -INFINITY;
        #pragma unroll
        for (int off = 1; off < 16; off <<= 1) v = fmaxf(v, __shfl_xor(v, off));
        if (lane == 0) s_zmB = v;
    }
    __syncthreads();                                           // B2
    const float zmA = s_zmA, zmB = s_zmB;
    const float TLA = zmA - 1.0f, TLB = zmB - 1.0f;

    // ---- P2: register pass — 4-level g sums for both rows ----
    float a0 = 0.f, a1 = 0.f, a2 = 0.f, a3 = 0.f;
    float b0 = 0.f, b1 = 0.f, b2 = 0.f, b3 = 0.f;
    #pragma unroll
    for (int it = 0; it < F4R; ++it) {
        float4 va = zrA[it], vb = zrB[it];
        #pragma unroll
        for (int e = 0; e < 4; ++e) {
            float za = (e == 0) ? va.x : (e == 1) ? va.y : (e == 2) ? va.z : va.w;
            float d3 = za - TLA;
            if (d3 > 0.f) {
                a3 = fmaf(d3, d3, a3);
                float d2 = d3 - 0.25f; if (d2 > 0.f) a2 = fmaf(d2, d2, a2);
                float d1 = d3 - 0.50f; if (d1 > 0.f) a1 = fmaf(d1, d1, a1);
                float d0 = d3 - 0.75f; if (d0 > 0.f) a0 = fmaf(d0, d0, a0);
            }
            float zb = (e == 0) ? vb.x : (e == 1) ? vb.y : (e == 2) ? vb.z : vb.w;
            float e3 = zb - TLB;
            if (e3 > 0.f) {
                b3 = fmaf(e3, e3, b3);
                float e2 = e3 - 0.25f; if (e2 > 0.f) b2 = fmaf(e2, e2, b2);
                float e1 = e3 - 0.50f; if (e1 > 0.f) b1 = fmaf(e1, e1, b1);
                float e0 = e3 - 0.75f; if (e0 > 0.f) b0 = fmaf(e0, e0, b0);
            }
        }
    }
    #pragma unroll
    for (int off = 1; off < 64; off <<= 1) {
        a0 += __shfl_xor(a0, off); a1 += __shfl_xor(a1, off);
        a2 += __shfl_xor(a2, off); a3 += __shfl_xor(a3, off);
        b0 += __shfl_xor(b0, off); b1 += __shfl_xor(b1, off);
        b2 += __shfl_xor(b2, off); b3 += __shfl_xor(b3, off);
    }
    if (lane == 0) {
        redA[0][wid] = a0; redA[1][wid] = a1; redA[2][wid] = a2; redA[3][wid] = a3;
        redB[0][wid] = b0; redB[1][wid] = b1; redB[2][wid] = b2; redB[3][wid] = b3;
    }
    __syncthreads();                                           // B3
    if (wid == 0) {                        // pick tightest level with g >= 1.02 (row A)
        int j = lane >> 4, idx = lane & 15;
        float v = redA[j][idx];
        #pragma unroll
        for (int off = 1; off < 16; off <<= 1) v += __shfl_xor(v, off);
        float G0 = __shfl(v, 0), G1 = __shfl(v, 16), G2 = __shfl(v, 32);
        if (lane == 0) {
            float T = TLA;
            if      (G0 >= 1.02f) T = zmA - 0.25f;
            else if (G1 >= 1.02f) T = zmA - 0.50f;
            else if (G2 >= 1.02f) T = zmA - 0.75f;
            s_TA = T;
        }
    } else if (wid == 1) {                 // row B
        int j = lane >> 4, idx = lane & 15;
        float v = redB[j][idx];
        #pragma unroll
        for (int off = 1; off < 16; off <<= 1) v += __shfl_xor(v, off);
        float G0 = __shfl(v, 0), G1 = __shfl(v, 16), G2 = __shfl(v, 32);
        if (lane == 0) {
            float T = TLB;
            if      (G0 >= 1.02f) T = zmB - 0.25f;
            else if (G1 >= 1.02f) T = zmB - 0.50f;
            else if (G2 >= 1.02f) T = zmB - 0.75f;
            s_TB = T;
        }
    }
    __syncthreads();                                           // B4
    const float TA = s_TA, TB = s_TB;

    // ---- P3: ballot-compacted collection (one atomic per wave-group) ----
    const unsigned long long ltmask = (1ull << lane) - 1ull;
    #pragma unroll
    for (int it = 0; it < F4R; ++it) {
        float4 va = zrA[it], vb = zrB[it];
        #pragma unroll
        for (int e = 0; e < 4; ++e) {
            float za = (e == 0) ? va.x : (e == 1) ? va.y : (e == 2) ? va.z : va.w;
            bool pa = (za > TA);
            unsigned long long ma = __ballot(pa);
            if (ma) {
                int base = 0;
                if (lane == 0) base = atomicAdd(&s_cntA, (int)__popcll(ma));
                base = __shfl(base, 0);
                if (pa) {
                    int p = base + (int)__popcll(ma & ltmask);
                    if (p < CCAP) candA[p] = za;
                }
            }
            float zb = (e == 0) ? vb.x : (e == 1) ? vb.y : (e == 2) ? vb.z : vb.w;
            bool pb = (zb > TB);
            unsigned long long mb = __ballot(pb);
            if (mb) {
                int base = 0;
                if (lane == 0) base = atomicAdd(&s_cntB, (int)__popcll(mb));
                base = __shfl(base, 0);
                if (pb) {
                    int p = base + (int)__popcll(mb & ltmask);
                    if (p < CCAP) candB[p] = zb;
                }
            }
        }
    }
    __syncthreads();                                           // B5

    // ---- P4: dual parallel solves — wave 0: row A, wave 1: row B ----
    if (wid < 2) {
        float* cand = (wid == 0) ? candA : candB;
        const int   C  = min((wid == 0) ? s_cntA : s_cntB, CCAP);
        const float T  = (wid == 0) ? TA : TB;
        const float zm = (wid == 0) ? zmA : zmB;
        if (lane < 4) cand[C + lane] = -INFINITY;   // float4 pad (wave-internal)
        const int C4 = (C + 3) >> 2;
        const float4* c4 = (const float4*)cand;
        // bracket [T, zm]: g(T) >= 1, g(zm) = 0
        float lo = T, hi = zm;
        for (int round = 0; round < 3; ++round) {
            float h = (hi - lo) * 0.015625f;        // /64
            float t = fmaf(h, (float)(lane + 1), lo);
            float g = 0.f;
            for (int i = 0; i < C4; ++i) {          // broadcast reads, conflict-free
                float4 v = c4[i]; float d;
                d = v.x - t; if (d > 0.f) g = fmaf(d, d, g);
                d = v.y - t; if (d > 0.f) g = fmaf(d, d, g);
                d = v.z - t; if (d > 0.f) g = fmaf(d, d, g);
                d = v.w - t; if (d > 0.f) g = fmaf(d, d, g);
            }
            unsigned long long bal = __ballot(g >= 1.f);   // monotone: low lanes set
            float lo_old = lo;
            if (bal == 0ull) hi = lo_old + h;
            else {
                int j = 63 - (int)__clzll((long long)bal);
                lo = fmaf(h, (float)(j + 1), lo_old);
                hi = fmaf(h, (float)(j + 2), lo_old);
            }
        }
        // fixed-point refinement with exact reference formula (redundant per-lane)
        float tau = lo;
        for (int r = 0; r < 3; ++r) {
            float k = 0.f, s1 = 0.f, s2 = 0.f;
            for (int i = 0; i < C4; ++i) {
                float4 v = c4[i];
                if (v.x > tau) { k += 1.f; s1 += v.x; s2 = fmaf(v.x, v.x, s2); }
                if (v.y > tau) { k += 1.f; s1 += v.y; s2 = fmaf(v.y, v.y, s2); }
                if (v.z > tau) { k += 1.f; s1 += v.z; s2 = fmaf(v.z, v.z, s2); }
                if (v.w > tau) { k += 1.f; s1 += v.w; s2 = fmaf(v.w, v.w, s2); }
            }
            if (k < 0.5f) break;
            float mean  = s1 / k;
            float ss    = s2 - mean * s1;           // S2 - S1^2/k
            float delta = fmaxf((1.f - ss) / k, 0.f);
            tau = mean - sqrtf(delta);
        }
        // normalizer S = sum clip(z - tau)^2 (cand covers all positives: tau >= T)
        float ps = 0.f;
        for (int i = 0; i < C4; ++i) {
            float4 v = c4[i]; float d;
            d = v.x - tau; if (d > 0.f) ps = fmaf(d, d, ps);
            d = v.y - tau; if (d > 0.f) ps = fmaf(d, d, ps);
            d = v.z - tau; if (d > 0.f) ps = fmaf(d, d, ps);
            d = v.w - tau; if (d > 0.f) ps = fmaf(d, d, ps);
        }
        if (lane == 0) {
            if (wid == 0) { s_tauA = tau; s_SA = ps; }
            else          { s_tauB = tau; s_SB = ps; }
        }
    }
    __syncthreads();                                           // B6
    const float tauA = s_tauA, rnA = 1.0f / (s_SA + 1e-8f);
    const float tauB = s_tauB, rnB = 1.0f / (s_SB + 1e-8f);

    // ---- P5: apply from registers, non-temporal write, count ----
    int lcA = 0, lcB = 0;
    #pragma unroll
    for (int it = 0; it < F4R; ++it) {
        float4 va = zrA[it];
        f32x4 w; float d;
        d = fmaxf(va.x - tauA, 0.f); w.x = d * d * rnA; lcA += (w.x > 1e-6f);
        d = fmaxf(va.y - tauA, 0.f); w.y = d * d * rnA; lcA += (w.y > 1e-6f);
        d = fmaxf(va.z - tauA, 0.f); w.z = d * d * rnA; lcA += (w.z > 1e-6f);
        d = fmaxf(va.w - tauA, 0.f); w.w = d * d * rnA; lcA += (w.w > 1e-6f);
        __builtin_nontemporal_store(w, &wpA[it * NT + tid]);
        float4 vb = zrB[it];
        d = fmaxf(vb.x - tauB, 0.f); w.x = d * d * rnB; lcB += (w.x > 1e-6f);
        d = fmaxf(vb.y - tauB, 0.f); w.y = d * d * rnB; lcB += (w.y > 1e-6f);
        d = fmaxf(vb.z - tauB, 0.f); w.z = d * d * rnB; lcB += (w.z > 1e-6f);
        d = fmaxf(vb.w - tauB, 0.f); w.w = d * d * rnB; lcB += (w.w > 1e-6f);
        __builtin_nontemporal_store(w, &wpB[it * NT + tid]);
    }
    #pragma unroll
    for (int off = 32; off; off >>= 1) {
        lcA += __shfl_down(lcA, off);
        lcB += __shfl_down(lcB, off);
    }
    if (lane == 0) { atomicAdd(&s_nselA, lcA); atomicAdd(&s_nselB, lcB); }
    __syncthreads();                                           // B7
    if (tid == 0) {
        outn[rowA] = (float)s_nselA;               // harness reads fp32
        outn[rowB] = (float)s_nselB;
    }
}

extern "C" void kernel_launch(void* const* d_in, const int* in_sizes, int n_in,
                              void* d_out, int out_size, void* d_ws, size_t ws_size,
                              hipStream_t stream) {
    const float* logits = (const float*)d_in[0];
    float* outw = (float*)d_out;
    float* outn = outw + (size_t)BROWS * NCOLS;
    entmax2<<<dim3(BROWS / 2), dim3(NT), 0, stream>>>(logits, outw, outn);
}